// Round 7
// baseline (1052.586 us; speedup 1.0000x reference)
//
#include <hip/hip_runtime.h>

typedef unsigned short u16;

static constexpr int BB = 16;    // batch
static constexpr int CC = 512;   // channels / embed dim
static constexpr int SS = 1024;  // seq = 32*32
static constexpr int R  = 256;   // q-chunk rows

__device__ __forceinline__ u16 f2bf(float f) {
  __bf16 h = (__bf16)f; return __builtin_bit_cast(unsigned short, h);
}
__device__ __forceinline__ float bf2f(u16 u) {
  union { unsigned int i; float f; } v; v.i = ((unsigned int)u) << 16; return v.f;
}

// ---------------- BatchNorm stats per channel over (B,S), fp64 ----------------
__global__ __launch_bounds__(256) void bn_stats_f64(const float* __restrict__ x, double* __restrict__ stats) {
  const int c = blockIdx.x;
  double s = 0.0, s2 = 0.0;
  for (int n = threadIdx.x; n < BB * SS; n += 256) {
    int b = n >> 10, sp = n & (SS - 1);
    double v = (double)x[((long long)(b * CC + c)) * SS + sp];
    s += v; s2 += v * v;
  }
  __shared__ double sh[256], sh2[256];
  sh[threadIdx.x] = s; sh2[threadIdx.x] = s2;
  __syncthreads();
  for (int off = 128; off > 0; off >>= 1) {
    if (threadIdx.x < off) { sh[threadIdx.x] += sh[threadIdx.x + off]; sh2[threadIdx.x] += sh2[threadIdx.x + off]; }
    __syncthreads();
  }
  if (threadIdx.x == 0) {
    const double n = 16384.0;
    double mean = sh[0] / n;
    double var = sh2[0] / n - mean * mean;   // biased variance (torch BN training stats)
    stats[c] = mean;
    stats[CC + c] = 1.0 / sqrt(var + 1e-5);
  }
}

// ---------------- normalize + transpose: x [b,c,s] -> xn [b,s,c] fp32 ----------------
__global__ __launch_bounds__(256) void bn_apply_transpose(const float* __restrict__ x,
                                                          const double* __restrict__ stats,
                                                          float* __restrict__ xn) {
  __shared__ float tile[64][65];
  const int b = blockIdx.z;
  const int s0 = blockIdx.x * 64, c0 = blockIdx.y * 64;
  const int t = threadIdx.x & 63, rb = threadIdx.x >> 6;
#pragma unroll
  for (int r0 = 0; r0 < 64; r0 += 4) {
    int r = r0 + rb;
    int c = c0 + r;
    double v = (double)x[((long long)(b * CC + c)) * SS + s0 + t];
    tile[r][t] = (float)((v - stats[c]) * stats[CC + c]);
  }
  __syncthreads();
#pragma unroll
  for (int r0 = 0; r0 < 64; r0 += 4) {
    int r = r0 + rb;
    xn[((long long)(b * SS + s0 + r)) * CC + c0 + t] = tile[t][r];
  }
}

// ---------------- NT GEMM fp32: C[z][m][n] = scale * sum_k A[z][m][k] * Bt[z][n][k] ----------------
__global__ __launch_bounds__(256) void gemm_nt_f32(
    const float* __restrict__ A, long long sA, const float* __restrict__ Bt, long long sB,
    float* __restrict__ C, long long sC, int M, int N, int K, float scale) {
  __shared__ float sa[16][68];
  __shared__ float sb[16][68];
  const float* Az = A + (long long)blockIdx.z * sA;
  const float* Bz = Bt + (long long)blockIdx.z * sB;
  const int tid = threadIdx.x;
  const int tx = tid & 15, ty = tid >> 4;
  const int m0 = blockIdx.y * 64, n0 = blockIdx.x * 64;
  const int lrow = tid & 63, kq = (tid >> 6) * 4;
  float acc[4][4] = {};
  for (int k0 = 0; k0 < K; k0 += 16) {
    float4 a4 = *reinterpret_cast<const float4*>(&Az[(long long)(m0 + lrow) * K + k0 + kq]);
    float4 b4 = *reinterpret_cast<const float4*>(&Bz[(long long)(n0 + lrow) * K + k0 + kq]);
    sa[kq + 0][lrow] = a4.x; sa[kq + 1][lrow] = a4.y; sa[kq + 2][lrow] = a4.z; sa[kq + 3][lrow] = a4.w;
    sb[kq + 0][lrow] = b4.x; sb[kq + 1][lrow] = b4.y; sb[kq + 2][lrow] = b4.z; sb[kq + 3][lrow] = b4.w;
    __syncthreads();
#pragma unroll
    for (int kk = 0; kk < 16; kk++) {
      const float* ar = &sa[kk][ty * 4];
      const float* br = &sb[kk][tx * 4];
#pragma unroll
      for (int i = 0; i < 4; i++)
#pragma unroll
        for (int j = 0; j < 4; j++) acc[i][j] += ar[i] * br[j];
    }
    __syncthreads();
  }
  float* Cz = C + (long long)blockIdx.z * sC;
#pragma unroll
  for (int i = 0; i < 4; i++) {
    float4 r;
    r.x = acc[i][0] * scale; r.y = acc[i][1] * scale; r.z = acc[i][2] * scale; r.w = acc[i][3] * scale;
    *reinterpret_cast<float4*>(&Cz[(long long)(m0 + ty * 4 + i) * N + n0 + tx * 4]) = r;
  }
}

// ---------------- NN GEMM: C[z][m][n] = sum_k A[z][m][k] * B[z][k][n] ----------------
// BBF16: B is bf16.  OUTBF16: store bf16.
template <bool BBF16, bool OUTBF16>
__global__ __launch_bounds__(256) void gemm_nn(
    const float* __restrict__ A, long long sA, const void* __restrict__ B, long long sB,
    void* __restrict__ C, long long sC, int M, int N, int K) {
  __shared__ float sa[16][68];
  __shared__ float sb[16][68];
  const float* Az = A + (long long)blockIdx.z * sA;
  const int tid = threadIdx.x;
  const int tx = tid & 15, ty = tid >> 4;
  const int m0 = blockIdx.y * 64, n0 = blockIdx.x * 64;
  const int lrow = tid & 63, kq = (tid >> 6) * 4;   // A staging: 64 rows x 16 k
  const int krow = tid >> 4, nc = tid & 15;         // B staging: 16 k x 64 n
  float acc[4][4] = {};
  for (int k0 = 0; k0 < K; k0 += 16) {
    float4 a4 = *reinterpret_cast<const float4*>(&Az[(long long)(m0 + lrow) * K + k0 + kq]);
    sa[kq + 0][lrow] = a4.x; sa[kq + 1][lrow] = a4.y; sa[kq + 2][lrow] = a4.z; sa[kq + 3][lrow] = a4.w;
    if constexpr (BBF16) {
      const u16* Bz = reinterpret_cast<const u16*>(B) + (long long)blockIdx.z * sB;
      ushort4 b4 = *reinterpret_cast<const ushort4*>(&Bz[(long long)(k0 + krow) * N + n0 + nc * 4]);
      sb[krow][nc * 4 + 0] = bf2f(b4.x); sb[krow][nc * 4 + 1] = bf2f(b4.y);
      sb[krow][nc * 4 + 2] = bf2f(b4.z); sb[krow][nc * 4 + 3] = bf2f(b4.w);
    } else {
      const float* Bz = reinterpret_cast<const float*>(B) + (long long)blockIdx.z * sB;
      *reinterpret_cast<float4*>(&sb[krow][nc * 4]) =
          *reinterpret_cast<const float4*>(&Bz[(long long)(k0 + krow) * N + n0 + nc * 4]);
    }
    __syncthreads();
#pragma unroll
    for (int kk = 0; kk < 16; kk++) {
      const float* ar = &sa[kk][ty * 4];
      const float* br = &sb[kk][tx * 4];
#pragma unroll
      for (int i = 0; i < 4; i++)
#pragma unroll
        for (int j = 0; j < 4; j++) acc[i][j] += ar[i] * br[j];
    }
    __syncthreads();
  }
#pragma unroll
  for (int i = 0; i < 4; i++) {
    long long row = (long long)(m0 + ty * 4 + i) * N + n0 + tx * 4;
    if constexpr (OUTBF16) {
      u16* Cz = reinterpret_cast<u16*>(C) + (long long)blockIdx.z * sC;
#pragma unroll
      for (int j = 0; j < 4; j++) Cz[row + j] = f2bf(acc[i][j]);
    } else {
      float* Cz = reinterpret_cast<float*>(C) + (long long)blockIdx.z * sC;
      float4 r; r.x = acc[i][0]; r.y = acc[i][1]; r.z = acc[i][2]; r.w = acc[i][3];
      *reinterpret_cast<float4*>(&Cz[row]) = r;
    }
  }
}

// ---------------- softmax over batch axis (Softmax2d dim=-3 quirk), in-place fp32 ----------------
__global__ __launch_bounds__(256) void softmax_batch_inplace(float* __restrict__ sc, long long plane) {
  long long idx = (long long)blockIdx.x * 256 + threadIdx.x;
  float v[16];
  float m = -3.4e38f;
#pragma unroll
  for (int b = 0; b < 16; b++) { v[b] = sc[(long long)b * plane + idx]; m = fmaxf(m, v[b]); }
  float s = 0.f;
#pragma unroll
  for (int b = 0; b < 16; b++) { v[b] = expf(v[b] - m); s += v[b]; }
  float inv = 1.f / s;
#pragma unroll
  for (int b = 0; b < 16; b++) sc[(long long)b * plane + idx] = v[b] * inv;
}

// ---------------- out(FP32) = attn + xn for one q-chunk ----------------
__global__ __launch_bounds__(256) void residual_store_f32(const float* __restrict__ attn,
                                                          const float* __restrict__ xn,
                                                          float* __restrict__ out, int s0c) {
  long long idx = (long long)blockIdx.x * 256 + threadIdx.x;  // over 16*R*512
  long long rs = (long long)R * 512;
  int b = (int)(idx / rs);
  long long rem = idx - (long long)b * rs;
  int s = (int)(rem >> 9);
  int d = (int)(rem & 511);
  long long xidx = ((long long)(b * SS + s0c + s)) * CC + d;
  out[xidx] = attn[idx] + xn[xidx];
}

extern "C" void kernel_launch(void* const* d_in, const int* in_sizes, int n_in,
                              void* d_out, int out_size, void* d_ws, size_t ws_size,
                              hipStream_t stream) {
  (void)in_sizes; (void)n_in; (void)out_size; (void)ws_size;
  const float* x  = (const float*)d_in[0];
  const float* Qw = (const float*)d_in[1];
  const float* Kw = (const float*)d_in[2];
  const float* Vw = (const float*)d_in[3];
  float* out = (float*)d_out;                 // OUTPUT IS FP32 (decoded round 6)
  char* ws = (char*)d_ws;

  // ws layout, total ~73.1 MB (< proven 86 MB floor)
  double* stats = (double*)(ws + 256);        // 8 KB    [mean | inv_std] fp64
  float*  W2    = (float*)(ws + 8960);        // 1 MB    [c][c'] = sum_d Q[c,d] K[c',d]
  float*  xn    = (float*)(ws + 1057536);     // 32 MB   [16,1024,512] fp32
  u16*    vb    = (u16*)(ws + 34611968);      // 16 MB   [16,1024,512] bf16 (v = xn @ V)
  float*  tbuf  = (float*)(ws + 51389184);    //  8 MB   [16,R,512] fp32 (t, then attn)
  float*  scomp = (float*)(ws + 59777792);    // 16 MB   [16,R,1024] fp32

  bn_stats_f64<<<CC, 256, 0, stream>>>(x, stats);
  bn_apply_transpose<<<dim3(SS / 64, CC / 64, BB), 256, 0, stream>>>(x, stats, xn);

  // Literal reference orientation: q = xn @ Q, k = xn @ K  =>  scores = xn (Q K^T) xn^T / sqrt(C)
  // W2[c][c'] = sum_d Q[c,d] * K[c',d]   (NT over rows of Q, rows of K)
  gemm_nt_f32<<<dim3(8, 8, 1), 256, 0, stream>>>(Qw, 0, Kw, 0, W2, 0, 512, 512, 512, 1.0f);

  // v = xn @ V -> bf16 [16384, 512]
  gemm_nn<false, true><<<dim3(8, 256, 1), 256, 0, stream>>>(xn, 0, Vw, 0, vb, 0, 16384, 512, 512);

  const float scale = 0.04419417382415922f;  // 1/sqrt(512)
  for (int ci = 0; ci < 4; ci++) {
    int s0c = ci * R;
    // t[b,s,c'] = sum_c xn[b,s0c+s,c] * W2[c][c']
    gemm_nn<false, false><<<dim3(8, R / 64, 16), 256, 0, stream>>>(
        xn + (long long)s0c * 512, 524288LL, W2, 0, tbuf, (long long)R * 512, R, 512, 512);
    // scores[b,q,j] = scale * sum_c' t[b,q,c'] * xn[b,j,c']
    gemm_nt_f32<<<dim3(16, R / 64, 16), 256, 0, stream>>>(
        tbuf, (long long)R * 512, xn, 524288LL, scomp, (long long)R * 1024, R, 1024, 512, scale);
    // softmax over the 16 batches, in place
    softmax_batch_inplace<<<(unsigned)(R * 4), 256, 0, stream>>>(scomp, (long long)R * 1024);
    // attn[b,q,d] = sum_k w[b,q,k] * v[b,k,d]  (reuse tbuf)
    gemm_nn<true, false><<<dim3(8, R / 64, 16), 256, 0, stream>>>(
        scomp, (long long)R * 1024, vb, 524288LL, tbuf, (long long)R * 512, R, 512, 1024);
    // out (fp32) = attn + xn
    residual_store_f32<<<(unsigned)(16LL * R * 512 / 256), 256, 0, stream>>>(tbuf, xn, out, s0c);
  }
}

// Round 8
// 533.269 us; speedup vs baseline: 1.9738x; 1.9738x over previous
//
#include <hip/hip_runtime.h>

typedef unsigned short u16;
typedef __bf16 bf16x8 __attribute__((ext_vector_type(8)));
typedef float f32x4 __attribute__((ext_vector_type(4)));

static constexpr int BB = 16;    // batch
static constexpr int CC = 512;   // channels
static constexpr int SS = 1024;  // seq
static constexpr int R  = 256;   // q-chunk rows

__device__ __forceinline__ u16 f2bf(float f) {
  __bf16 h = (__bf16)f; return __builtin_bit_cast(unsigned short, h);
}
__device__ __forceinline__ float bf2f(u16 u) {
  union { unsigned int i; float f; } v; v.i = ((unsigned int)u) << 16; return v.f;
}
__device__ __forceinline__ void split2(float v, u16& hi, u16& lo) {
  __bf16 h = (__bf16)v;
  float hf = (float)h;
  __bf16 l = (__bf16)(v - hf);
  hi = __builtin_bit_cast(unsigned short, h);
  lo = __builtin_bit_cast(unsigned short, l);
}

// ---------------- BatchNorm stats per channel over (B,S), fp64 ----------------
__global__ __launch_bounds__(256) void bn_stats_f64(const float* __restrict__ x, double* __restrict__ stats) {
  const int c = blockIdx.x;
  double s = 0.0, s2 = 0.0;
  for (int n = threadIdx.x; n < BB * SS; n += 256) {
    int b = n >> 10, sp = n & (SS - 1);
    double v = (double)x[((long long)(b * CC + c)) * SS + sp];
    s += v; s2 += v * v;
  }
  __shared__ double sh[256], sh2[256];
  sh[threadIdx.x] = s; sh2[threadIdx.x] = s2;
  __syncthreads();
  for (int off = 128; off > 0; off >>= 1) {
    if (threadIdx.x < off) { sh[threadIdx.x] += sh[threadIdx.x + off]; sh2[threadIdx.x] += sh2[threadIdx.x + off]; }
    __syncthreads();
  }
  if (threadIdx.x == 0) {
    double mean = sh[0] / 16384.0;
    double var = sh2[0] / 16384.0 - mean * mean;   // biased (torch BN)
    stats[c] = mean;
    stats[CC + c] = 1.0 / sqrt(var + 1e-5);
  }
}

// ---------------- normalize + transpose + split: x [b,c,s] -> xnh/xnl bf16 [b*S + s][c] ----------------
__global__ __launch_bounds__(256) void bn_apply_split(const float* __restrict__ x,
                                                      const double* __restrict__ stats,
                                                      u16* __restrict__ xnh, u16* __restrict__ xnl) {
  __shared__ float tile[64][65];
  const int b = blockIdx.z;
  const int s0 = blockIdx.x * 64, c0 = blockIdx.y * 64;
  const int t = threadIdx.x & 63, rb = threadIdx.x >> 6;
#pragma unroll
  for (int r0 = 0; r0 < 64; r0 += 4) {
    int r = r0 + rb;
    int c = c0 + r;
    double v = (double)x[((long long)(b * CC + c)) * SS + s0 + t];
    tile[r][t] = (float)((v - stats[c]) * stats[CC + c]);
  }
  __syncthreads();
#pragma unroll
  for (int r0 = 0; r0 < 64; r0 += 4) {
    int r = r0 + rb;
    long long idx = ((long long)(b * SS + s0 + r)) * CC + c0 + t;
    u16 h, l; split2(tile[t][r], h, l);
    xnh[idx] = h; xnl[idx] = l;
  }
}

// ---------------- fp32 [n] -> bf16 hi/lo planes ----------------
__global__ __launch_bounds__(256) void conv_split(const float* __restrict__ src,
                                                  u16* __restrict__ h, u16* __restrict__ l) {
  int i = (blockIdx.x * 256 + threadIdx.x) * 4;
  float4 f = *reinterpret_cast<const float4*>(src + i);
  ushort4 H, L;
  split2(f.x, H.x, L.x); split2(f.y, H.y, L.y); split2(f.z, H.z, L.z); split2(f.w, H.w, L.w);
  *reinterpret_cast<ushort4*>(h + i) = H;
  *reinterpret_cast<ushort4*>(l + i) = L;
}

// ---------------- V fp32 [c][d] -> Vt bf16 [d][c] ----------------
__global__ __launch_bounds__(256) void trans_conv_v(const float* __restrict__ V, u16* __restrict__ Vt) {
  __shared__ float tile[64][65];
  const int c0 = blockIdx.x * 64, d0 = blockIdx.y * 64;
  const int t = threadIdx.x & 63, rb = threadIdx.x >> 6;
#pragma unroll
  for (int r0 = 0; r0 < 64; r0 += 4) {
    int r = r0 + rb;
    tile[r][t] = V[(long long)(c0 + r) * 512 + d0 + t];
  }
  __syncthreads();
#pragma unroll
  for (int r0 = 0; r0 < 64; r0 += 4) {
    int r = r0 + rb;
    Vt[(long long)(d0 + r) * 512 + c0 + t] = f2bf(tile[t][r]);
  }
}

// ---------------- MFMA NT GEMM, 128x128 tile, BK=32, optional hi/lo split on A/B ----------------
// C[z][m][n] = sum_k A[z][m][k] * Bt[z][n][k]  (split planes approximate fp32 inputs; lo*lo dropped)
// OUTMODE 0: fp32 = acc*scale. 1: bf16. 2: split hi/lo to C,C2. 3: fp32 = acc + (Rh+Rl) residual.
template <bool ASPLIT, bool BSPLIT, int OUTMODE>
__global__ __launch_bounds__(256) void mfma_nt(
    const u16* __restrict__ Ah, const u16* __restrict__ Al, long long sA,
    const u16* __restrict__ Bh, const u16* __restrict__ Bl, long long sB,
    void* __restrict__ C, void* __restrict__ C2, long long sC,
    int N, int K, float scale, const u16* __restrict__ Rh, const u16* __restrict__ Rl) {
  __shared__ __attribute__((aligned(16))) u16 lah[128 * 32];
  __shared__ __attribute__((aligned(16))) u16 lal[ASPLIT ? 128 * 32 : 8];
  __shared__ __attribute__((aligned(16))) u16 lbh[128 * 32];
  __shared__ __attribute__((aligned(16))) u16 lbl[BSPLIT ? 128 * 32 : 8];

  const int tid = threadIdx.x;
  const int z = blockIdx.z;
  const int m0 = blockIdx.y * 128, n0 = blockIdx.x * 128;
  const int wave = tid >> 6, lane = tid & 63;
  const int wr = (wave >> 1) * 64, wc = (wave & 1) * 64;
  const int lrow = lane & 15, lquad = lane >> 4;
  const long long aB = (long long)z * sA, bB = (long long)z * sB;
  const int srow = tid >> 2, scg = (tid & 3) * 8;

  f32x4 acc[4][4];
#pragma unroll
  for (int i = 0; i < 4; i++)
#pragma unroll
    for (int j = 0; j < 4; j++) acc[i][j] = (f32x4){0.f, 0.f, 0.f, 0.f};

  for (int k0 = 0; k0 < K; k0 += 32) {
    *reinterpret_cast<uint4*>(&lah[srow * 32 + scg]) =
        *reinterpret_cast<const uint4*>(Ah + aB + (long long)(m0 + srow) * K + k0 + scg);
    *reinterpret_cast<uint4*>(&lah[(srow + 64) * 32 + scg]) =
        *reinterpret_cast<const uint4*>(Ah + aB + (long long)(m0 + srow + 64) * K + k0 + scg);
    if constexpr (ASPLIT) {
      *reinterpret_cast<uint4*>(&lal[srow * 32 + scg]) =
          *reinterpret_cast<const uint4*>(Al + aB + (long long)(m0 + srow) * K + k0 + scg);
      *reinterpret_cast<uint4*>(&lal[(srow + 64) * 32 + scg]) =
          *reinterpret_cast<const uint4*>(Al + aB + (long long)(m0 + srow + 64) * K + k0 + scg);
    }
    *reinterpret_cast<uint4*>(&lbh[srow * 32 + scg]) =
        *reinterpret_cast<const uint4*>(Bh + bB + (long long)(n0 + srow) * K + k0 + scg);
    *reinterpret_cast<uint4*>(&lbh[(srow + 64) * 32 + scg]) =
        *reinterpret_cast<const uint4*>(Bh + bB + (long long)(n0 + srow + 64) * K + k0 + scg);
    if constexpr (BSPLIT) {
      *reinterpret_cast<uint4*>(&lbl[srow * 32 + scg]) =
          *reinterpret_cast<const uint4*>(Bl + bB + (long long)(n0 + srow) * K + k0 + scg);
      *reinterpret_cast<uint4*>(&lbl[(srow + 64) * 32 + scg]) =
          *reinterpret_cast<const uint4*>(Bl + bB + (long long)(n0 + srow + 64) * K + k0 + scg);
    }
    __syncthreads();

    bf16x8 ah[4], al[ASPLIT ? 4 : 1], bh[4], bl[BSPLIT ? 4 : 1];
#pragma unroll
    for (int i = 0; i < 4; i++) {
      ah[i] = *reinterpret_cast<const bf16x8*>(&lah[(wr + i * 16 + lrow) * 32 + lquad * 8]);
      if constexpr (ASPLIT)
        al[i] = *reinterpret_cast<const bf16x8*>(&lal[(wr + i * 16 + lrow) * 32 + lquad * 8]);
      bh[i] = *reinterpret_cast<const bf16x8*>(&lbh[(wc + i * 16 + lrow) * 32 + lquad * 8]);
      if constexpr (BSPLIT)
        bl[i] = *reinterpret_cast<const bf16x8*>(&lbl[(wc + i * 16 + lrow) * 32 + lquad * 8]);
    }
#pragma unroll
    for (int i = 0; i < 4; i++)
#pragma unroll
      for (int j = 0; j < 4; j++) {
        f32x4 t = acc[i][j];
        if constexpr (ASPLIT) t = __builtin_amdgcn_mfma_f32_16x16x32_bf16(al[i], bh[j], t, 0, 0, 0);
        if constexpr (BSPLIT) t = __builtin_amdgcn_mfma_f32_16x16x32_bf16(ah[i], bl[j], t, 0, 0, 0);
        t = __builtin_amdgcn_mfma_f32_16x16x32_bf16(ah[i], bh[j], t, 0, 0, 0);
        acc[i][j] = t;
      }
    __syncthreads();
  }

  const long long zC = (long long)z * sC;
#pragma unroll
  for (int i = 0; i < 4; i++) {
    int rl_ = wr + i * 16 + lquad * 4;
#pragma unroll
    for (int j = 0; j < 4; j++) {
      int col = n0 + wc + j * 16 + lrow;
#pragma unroll
      for (int r = 0; r < 4; r++) {
        long long idx = zC + (long long)(m0 + rl_ + r) * N + col;
        float val = acc[i][j][r];
        if constexpr (OUTMODE == 0) {
          reinterpret_cast<float*>(C)[idx] = val * scale;
        } else if constexpr (OUTMODE == 1) {
          reinterpret_cast<u16*>(C)[idx] = f2bf(val);
        } else if constexpr (OUTMODE == 2) {
          u16 h, l; split2(val, h, l);
          reinterpret_cast<u16*>(C)[idx] = h;
          reinterpret_cast<u16*>(C2)[idx] = l;
        } else {
          reinterpret_cast<float*>(C)[idx] = val + bf2f(Rh[idx]) + bf2f(Rl[idx]);
        }
      }
    }
  }
}

// ---------------- softmax over batch axis: scomp fp32 -> attw bf16 ----------------
__global__ __launch_bounds__(256) void softmax_chunk(const float* __restrict__ sc,
                                                     u16* __restrict__ w) {
  long long idx = (long long)blockIdx.x * 256 + threadIdx.x;
  const long long plane = (long long)R * 1024;
  float v[16];
  float m = -3.4e38f;
#pragma unroll
  for (int b = 0; b < 16; b++) { v[b] = sc[(long long)b * plane + idx]; m = fmaxf(m, v[b]); }
  float s = 0.f;
#pragma unroll
  for (int b = 0; b < 16; b++) { v[b] = expf(v[b] - m); s += v[b]; }
  float inv = 1.f / s;
#pragma unroll
  for (int b = 0; b < 16; b++) w[(long long)b * plane + idx] = f2bf(v[b] * inv);
}

extern "C" void kernel_launch(void* const* d_in, const int* in_sizes, int n_in,
                              void* d_out, int out_size, void* d_ws, size_t ws_size,
                              hipStream_t stream) {
  (void)in_sizes; (void)n_in; (void)out_size; (void)ws_size;
  const float* x  = (const float*)d_in[0];
  const float* Qw = (const float*)d_in[1];
  const float* Kw = (const float*)d_in[2];
  const float* Vw = (const float*)d_in[3];
  float* out = (float*)d_out;   // fp32 output (decoded round 6, confirmed round 7)
  char* ws = (char*)d_ws;

  // ws layout, total 85,475,328 B — under the proven >=85,991,936 floor
  double* stats = (double*)(ws + 256);
  u16* xnh  = (u16*)(ws + 16384);        // [16384,512] bf16 hi   16 MB
  u16* xnl  = (u16*)(ws + 16793600);     // lo                     16 MB
  u16* Vt   = (u16*)(ws + 33570816);     // [512,512] bf16        0.5 MB
  u16* W2th = (u16*)(ws + 34095104);     // [c'][c] hi            0.5 MB
  u16* W2tl = (u16*)(ws + 34619392);     // lo                    0.5 MB
  u16* vt   = (u16*)(ws + 35143680);     // [16,512,1024] bf16     16 MB
  u16* th   = (u16*)(ws + 51920896);     // [16,256,512] hi         4 MB (aliases Q/K planes pre-loop)
  u16* tl   = (u16*)(ws + 56115200);     // lo                      4 MB
  float* scomp = (float*)(ws + 60309504);// [16,256,1024] fp32     16 MB
  u16* attw = (u16*)(ws + 77086720);     // [16,256,1024] bf16      8 MB
  // Q/K split planes (used only before the chunk loop) alias the th/tl region:
  u16* Qh = (u16*)(ws + 51920896);
  u16* Ql = (u16*)(ws + 52445184);
  u16* Kh = (u16*)(ws + 52969472);
  u16* Kl = (u16*)(ws + 53493760);

  bn_stats_f64<<<CC, 256, 0, stream>>>(x, stats);
  bn_apply_split<<<dim3(16, 8, 16), 256, 0, stream>>>(x, stats, xnh, xnl);
  conv_split<<<256, 256, 0, stream>>>(Qw, Qh, Ql);
  conv_split<<<256, 256, 0, stream>>>(Kw, Kh, Kl);
  trans_conv_v<<<dim3(8, 8), 256, 0, stream>>>(Vw, Vt);

  // W2t[c'][c] = sum_d K[c',d] Q[c,d]  (Bt layout for the t GEMM; split x split, split out)
  mfma_nt<true, true, 2><<<dim3(4, 4, 1), 256, 0, stream>>>(
      Kh, Kl, 0, Qh, Ql, 0, W2th, W2tl, 0, 512, 512, 1.0f, nullptr, nullptr);

  // vt[b][d][token] = sum_c Vt[d,c] * xn[b,token,c]   (A plain bf16, B split, bf16 out)
  mfma_nt<false, true, 1><<<dim3(8, 4, 16), 256, 0, stream>>>(
      Vt, nullptr, 0, xnh, xnl, 524288, vt, nullptr, 524288, 1024, 512, 1.0f, nullptr, nullptr);

  const float scale = 0.04419417382415922f;  // 1/sqrt(512)
  for (int ci = 0; ci < 4; ci++) {
    int s0c = ci * R;
    // t[b,q,c'] = sum_c xn[b,s0c+q,c] * W2t[c'][c]   (split x split, split out)
    mfma_nt<true, true, 2><<<dim3(4, 2, 16), 256, 0, stream>>>(
        xnh + (long long)s0c * 512, xnl + (long long)s0c * 512, 524288,
        W2th, W2tl, 0, th, tl, 131072, 512, 512, 1.0f, nullptr, nullptr);
    // scores[b,q,j] = scale * sum_c' t[b,q,c'] * xn[b,j,c']   (split x split, fp32 out)
    mfma_nt<true, true, 0><<<dim3(8, 2, 16), 256, 0, stream>>>(
        th, tl, 131072, xnh, xnl, 524288, scomp, nullptr, 262144,
        1024, 512, scale, nullptr, nullptr);
    softmax_chunk<<<1024, 256, 0, stream>>>(scomp, attw);
    // out[b,s0c+q,d] = sum_k attw[b,q,k] * vt[b,d,k]  + xn residual   (plain bf16, fp32 out)
    mfma_nt<false, false, 3><<<dim3(4, 2, 16), 256, 0, stream>>>(
        attw, nullptr, 262144, vt, nullptr, 524288,
        out + (long long)s0c * 512, nullptr, 524288, 512, 1024, 1.0f,
        xnh + (long long)s0c * 512, xnl + (long long)s0c * 512);
  }
}